// Round 10
// baseline (2075.539 us; speedup 1.0000x reference)
//
#include <hip/hip_runtime.h>

// Problem: VQ-VAE codebook. z [32,256,32,32] f32, emb [8192,256] f32.
// Outputs concatenated in d_out (f32): z_q [8388608], idx [32768] (as float), loss [1].
//
// Scratch layout inside d_out's z_q region (consumed before k_out overwrites it):
//   [0 .. 2097152)        embT  (256 x 8192)   transposed codebook
//   [2097152 .. 2105344)  se    (8192)         ||e_k||^2
//   [2105344 .. 2138112)  sz    (32768)        ||z_n||^2
#define ZQ_OFF   0
#define EMBT_OFF 0
#define SE_OFF   2097152
#define SZ_OFF   2105344
#define IDX_OFF  8388608
#define LOSS_OFF 8421376

// ---- transpose emb -> embT[d][k] (coalesced writes, scattered reads; 8 MB, tiny)
__global__ void k_prep_transpose(const float* __restrict__ emb, float* __restrict__ embT) {
    int u = blockIdx.x * 256 + threadIdx.x;      // 0 .. 2M, grid = 8192 blocks
    int d = u >> 13;
    int k = u & 8191;
    embT[u] = emb[(size_t)k * 256 + d];
}

// ---- se[k] = sum(emb[k]^2)  (order-insensitive; wave per code, butterfly reduce)
__global__ void k_se(const float* __restrict__ emb, float* __restrict__ se) {
    int w    = (blockIdx.x * 256 + threadIdx.x) >> 6;   // code id
    int lane = threadIdx.x & 63;
    float4 v = *(const float4*)(emb + (size_t)w * 256 + lane * 4);
    float s = v.x * v.x + v.y * v.y + v.z * v.z + v.w * v.w;
    #pragma unroll
    for (int off = 1; off < 64; off <<= 1) s += __shfl_xor(s, off);
    if (lane == 0) se[w] = s;
}

// ---- sz[n] = sum over c of z[b][c][hw]^2 (order-insensitive: same-binade shift invariance)
__global__ void k_sz(const float* __restrict__ z, float* __restrict__ sz) {
    int n  = blockIdx.x * 256 + threadIdx.x;  // grid = 128 blocks
    int b  = n >> 10, hw = n & 1023;
    const float* zp = z + (size_t)b * 262144 + hw;
    float acc = 0.f;
    #pragma unroll 8
    for (int c = 0; c < 256; ++c) { float v = zp[(size_t)c << 10]; acc += v * v; }
    sz[n] = acc;
}

// 128 FMAs for one d: 16 rows (4 float4 z, broadcast) x 8 codes (2 float4 ef)
#define FMA_BLOCK(Z, E0, E1) do {                                        \
    _Pragma("unroll")                                                     \
    for (int i_ = 0; i_ < 4; ++i_) {                                      \
        _Pragma("unroll")                                                 \
        for (int q_ = 0; q_ < 4; ++q_) {                                  \
            const float zx_ = ((const float*)&(Z)[i_])[q_];               \
            const int rr_ = i_ * 4 + q_;                                  \
            acc[rr_][0] = fmaf(zx_, (E0).x, acc[rr_][0]);                 \
            acc[rr_][1] = fmaf(zx_, (E0).y, acc[rr_][1]);                 \
            acc[rr_][2] = fmaf(zx_, (E0).z, acc[rr_][2]);                 \
            acc[rr_][3] = fmaf(zx_, (E0).w, acc[rr_][3]);                 \
            acc[rr_][4] = fmaf(zx_, (E1).x, acc[rr_][4]);                 \
            acc[rr_][5] = fmaf(zx_, (E1).y, acc[rr_][5]);                 \
            acc[rr_][6] = fmaf(zx_, (E1).z, acc[rr_][6]);                 \
            acc[rr_][7] = fmaf(zx_, (E1).w, acc[rr_][7]);                 \
        }                                                                 \
    }                                                                     \
} while (0)

// ---- main: exact-f32-replica distance + argmin.
// 256 thr = 4 waves; 16 rows/block; grid 2048. All waves cover all 16 rows (R=16/thread);
// waves split codes 4-ways within a 2048-code tile: wave w owns w*512..+511, lane j owns
// 8 codes. Deep software pipeline, 4 d per body: four 1-d ef buffers each reloaded
// immediately after last use and consumed one full body later (~1024 own-issue cycles in
// flight -> covers HBM-miss latency at 2 waves/SIMD); z double-buffered (read for d+1
// issued before FMA(d)), carried across bodies. No rotation movs (buffers redefined in
// place). Per-tile argmin folded into LDS cwd/cwk (full lowest-k tie-break).
// d_nk = fl( fl(sz_n + se_k) - 2*m_nk ),  m = sequential fmaf chain over d=0..255 (BLAS order)
__global__ __launch_bounds__(256, 2) void k_main(
    const float* __restrict__ z, const float* __restrict__ embT,
    const float* __restrict__ se, const float* __restrict__ sz,
    float* __restrict__ idxf, float* __restrict__ lossslot) {
    __shared__ float ztT[257][16];        // [d][row]; pad row 256 absorbs last body's z prefetch
    __shared__ float szs[16];
    __shared__ float cwd[4][16];          // [codegrp][row] best distance
    __shared__ int   cwk[4][16];          // matching code id
    const int tid = threadIdx.x;
    const int blk = blockIdx.x;           // grid = 2048
    const int n0  = blk * 16;
    const int b   = n0 >> 10, hw0 = n0 & 1023;

    // stage z tile transposed: ztT[c][n]; coalesced global reads over n;
    // LDS writes 2 lanes/bank (free)
    {
        const int n  = tid & 15;
        const int cg = tid >> 4;                        // 0..15
        const float* zp = z + (size_t)b * 262144 + hw0 + n;
        #pragma unroll
        for (int cc = 0; cc < 256; cc += 16)
            ztT[cc + cg][n] = zp[(size_t)(cc + cg) << 10];
        if (tid < 16) szs[tid] = sz[n0 + tid];
        if (tid < 64) { (&cwd[0][0])[tid] = 3.4e38f; (&cwk[0][0])[tid] = 0; }
    }
    __syncthreads();

    const int w = tid >> 6;       // wave 0..3 -> code quarter w*512 within each tile
    const int j = tid & 63;       // lane -> 8 codes

    for (int tile = 0; tile < 4; ++tile) {
        const int c0 = tile * 2048 + w * 512 + j * 8;
        const float* ep = embT + c0;

        float acc[16][8];
        #pragma unroll
        for (int rr = 0; rr < 16; ++rr)
            #pragma unroll
            for (int c = 0; c < 8; ++c) acc[rr][c] = 0.f;

        // prologue: ef buffers for d=0..3; z buffer A for d=0
        float4 zA[4], zB[4];
        #pragma unroll
        for (int i = 0; i < 4; ++i) zA[i] = *(const float4*)&ztT[0][i * 4];
        float4 e0a = *(const float4*)(ep);
        float4 e0b = *(const float4*)(ep + 4);
        float4 e1a = *(const float4*)(ep + (size_t)1 * 8192);
        float4 e1b = *(const float4*)(ep + (size_t)1 * 8192 + 4);
        float4 e2a = *(const float4*)(ep + (size_t)2 * 8192);
        float4 e2b = *(const float4*)(ep + (size_t)2 * 8192 + 4);
        float4 e3a = *(const float4*)(ep + (size_t)3 * 8192);
        float4 e3b = *(const float4*)(ep + (size_t)3 * 8192 + 4);

        #pragma unroll 1
        for (int d = 0; d < 256; d += 4) {
            // ---- d+0 : z for d+1 -> B, compute from zA/e0, reload e0 <- ef(d+4)
            #pragma unroll
            for (int i = 0; i < 4; ++i) zB[i] = *(const float4*)&ztT[d + 1][i * 4];
            FMA_BLOCK(zA, e0a, e0b);
            {
                const float* ef4 = ep + (size_t)(d + 4) * 8192;
                e0a = *(const float4*)(ef4);
                e0b = *(const float4*)(ef4 + 4);
            }
            // ---- d+1 : z for d+2 -> A, compute from zB/e1, reload e1 <- ef(d+5)
            #pragma unroll
            for (int i = 0; i < 4; ++i) zA[i] = *(const float4*)&ztT[d + 2][i * 4];
            FMA_BLOCK(zB, e1a, e1b);
            {
                const float* ef5 = ep + (size_t)(d + 5) * 8192;
                e1a = *(const float4*)(ef5);
                e1b = *(const float4*)(ef5 + 4);
            }
            // ---- d+2 : z for d+3 -> B, compute from zA/e2, reload e2 <- ef(d+6)
            #pragma unroll
            for (int i = 0; i < 4; ++i) zB[i] = *(const float4*)&ztT[d + 3][i * 4];
            FMA_BLOCK(zA, e2a, e2b);
            {
                const float* ef6 = ep + (size_t)(d + 6) * 8192;
                e2a = *(const float4*)(ef6);
                e2b = *(const float4*)(ef6 + 4);
            }
            // ---- d+3 : z for d+4 -> A (row 256 pad on last body), compute from zB/e3,
            //            reload e3 <- ef(d+7)
            #pragma unroll
            for (int i = 0; i < 4; ++i) zA[i] = *(const float4*)&ztT[d + 4][i * 4];
            FMA_BLOCK(zB, e3a, e3b);
            {
                const float* ef7 = ep + (size_t)(d + 7) * 8192;
                e3a = *(const float4*)(ef7);
                e3b = *(const float4*)(ef7 + 4);
            }
        }
        // tail prefetches read ef rows 256..259 = se/sz scratch region (valid, never used)
        // and ztT row 256 pad (garbage, never used).

        // epilogue: dq = fl( fl(sz+se) - 2m ); codes ascending; strict < keeps first min
        const float4 seA = *(const float4*)(se + c0);
        const float4 seB = *(const float4*)(se + c0 + 4);
        #pragma unroll
        for (int rr = 0; rr < 16; ++rr) {
            const float szv = szs[rr];
            float bd = 3.4e38f; int bk = 0;
            #pragma unroll
            for (int c = 0; c < 8; ++c) {
                const float sek = (c < 4) ? ((const float*)&seA)[c]
                                          : ((const float*)&seB)[c - 4];
                float A  = szv + sek;
                float dq = A - 2.0f * acc[rr][c];
                if (dq < bd) { bd = dq; bk = c0 + c; }
            }
            // butterfly across 64 lanes; tie-break lowest k
            #pragma unroll
            for (int off = 1; off < 64; off <<= 1) {
                float od = __shfl_xor(bd, off);
                int   ok = __shfl_xor(bk, off);
                if (od < bd || (od == bd && ok < bk)) { bd = od; bk = ok; }
            }
            if (j == 0) {
                float pd = cwd[w][rr]; int pk = cwk[w][rr];
                if (bd < pd || (bd == pd && bk < pk)) { cwd[w][rr] = bd; cwk[w][rr] = bk; }
            }
        }
    }
    __syncthreads();
    // merge the 4 code-group partials per row with full (d,k) tie-break
    if (tid < 16) {
        float d = cwd[0][tid]; int k = cwk[0][tid];
        #pragma unroll
        for (int ww = 1; ww < 4; ++ww) {
            float od = cwd[ww][tid]; int ok = cwk[ww][tid];
            if (od < d || (od == d && ok < k)) { d = od; k = ok; }
        }
        idxf[n0 + tid] = (float)k;
    }
    if (blk == 0 && tid == 0) *lossslot = 0.f;   // init loss accumulator (runs before k_out)
}

// ---- z_q (STE-exact) + loss partial sums
__global__ void k_out(const float* __restrict__ z, const float* __restrict__ emb,
                      const float* __restrict__ idxf, float* __restrict__ zq,
                      float* __restrict__ lossslot) {
    int u   = blockIdx.x * 256 + threadIdx.x;   // grid = 8192 blocks (2M threads)
    int cc4 = u >> 15;                          // 0..63 (uniform per block)
    int n   = u & 32767;
    int b   = n >> 10, hw = n & 1023;
    int k   = (int)idxf[n];
    const float4 q4 = *(const float4*)(emb + (size_t)k * 256 + cc4 * 4);
    float ls = 0.f;
    #pragma unroll
    for (int c = 0; c < 4; ++c) {
        size_t zi = (size_t)b * 262144 + (size_t)(cc4 * 4 + c) * 1024 + hw;
        float zv   = z[zi];
        float qv   = ((const float*)&q4)[c];
        float diff = qv - zv;        // fl(q - z)
        zq[zi]     = zv + diff;      // fl(z + fl(q - z))  == reference STE output
        ls += diff * diff;
    }
    #pragma unroll
    for (int off = 1; off < 64; off <<= 1) ls += __shfl_xor(ls, off);
    if ((threadIdx.x & 63) == 0) atomicAdd(lossslot, ls);
}

__global__ void k_fin(float* __restrict__ lossslot) {
    float S = *lossslot;
    float m = S / 8388608.0f;        // /2^23 exact scaling
    *lossslot = m + 0.25f * m;       // fl(m1 + fl(beta*m2)), m1==m2
}

extern "C" void kernel_launch(void* const* d_in, const int* in_sizes, int n_in,
                              void* d_out, int out_size, void* d_ws, size_t ws_size,
                              hipStream_t stream) {
    const float* z   = (const float*)d_in[0];
    const float* emb = (const float*)d_in[1];
    float* out  = (float*)d_out;
    float* embT = out + EMBT_OFF;
    float* se   = out + SE_OFF;
    float* sz   = out + SZ_OFF;
    float* idxf = out + IDX_OFF;
    float* loss = out + LOSS_OFF;

    k_prep_transpose<<<8192, 256, 0, stream>>>(emb, embT);
    k_se<<<2048, 256, 0, stream>>>(emb, se);
    k_sz<<<128, 256, 0, stream>>>(z, sz);
    k_main<<<2048, 256, 0, stream>>>(z, embT, se, sz, idxf, loss);
    k_out<<<8192, 256, 0, stream>>>(z, emb, idxf, out + ZQ_OFF, loss);
    k_fin<<<1, 1, 0, stream>>>(loss);
}

// Round 11
// 1989.820 us; speedup vs baseline: 1.0431x; 1.0431x over previous
//
#include <hip/hip_runtime.h>

// Problem: VQ-VAE codebook. z [32,256,32,32] f32, emb [8192,256] f32.
// Outputs concatenated in d_out (f32): z_q [8388608], idx [32768] (as float), loss [1].
//
// Scratch layout inside d_out's z_q region (consumed before k_out overwrites it):
//   [0 .. 2097152)        embT  (256 x 8192)   transposed codebook
//   [2097152 .. 2105344)  se    (8192)         ||e_k||^2
//   [2105344 .. 2138112)  sz    (32768)        ||z_n||^2
#define ZQ_OFF   0
#define EMBT_OFF 0
#define SE_OFF   2097152
#define SZ_OFF   2105344
#define IDX_OFF  8388608
#define LOSS_OFF 8421376

// ---- fused: transpose emb -> embT[d][k]  +  se[k] = sum(emb[k]^2)
// blocks < 8192: transpose (coalesced writes, scattered reads; 8 MB, tiny)
// blocks >= 8192: se (order-insensitive; wave per code, butterfly reduce)
__global__ void k_prep(const float* __restrict__ emb, float* __restrict__ embT,
                       float* __restrict__ se) {
    const int blk = blockIdx.x;
    if (blk < 8192) {
        int u = blk * 256 + threadIdx.x;             // 0 .. 2M
        int d = u >> 13;
        int k = u & 8191;
        embT[u] = emb[(size_t)k * 256 + d];
    } else {
        int w    = ((blk - 8192) * 256 + threadIdx.x) >> 6;   // code id
        int lane = threadIdx.x & 63;
        float4 v = *(const float4*)(emb + (size_t)w * 256 + lane * 4);
        float s = v.x * v.x + v.y * v.y + v.z * v.z + v.w * v.w;
        #pragma unroll
        for (int off = 1; off < 64; off <<= 1) s += __shfl_xor(s, off);
        if (lane == 0) se[w] = s;
    }
}

// ---- sz[n] = sum over c of z[b][c][hw]^2 (order-insensitive: same-binade shift invariance)
__global__ void k_sz(const float* __restrict__ z, float* __restrict__ sz) {
    int n  = blockIdx.x * 256 + threadIdx.x;  // grid = 128 blocks
    int b  = n >> 10, hw = n & 1023;
    const float* zp = z + (size_t)b * 262144 + hw;
    float acc = 0.f;
    #pragma unroll 8
    for (int c = 0; c < 256; ++c) { float v = zp[(size_t)c << 10]; acc += v * v; }
    sz[n] = acc;
}

// 128 FMAs for one d: 16 rows (4 float4 z, broadcast) x 8 codes (2 float4 ef)
#define FMA_BLOCK(Z, E0, E1) do {                                        \
    _Pragma("unroll")                                                     \
    for (int i_ = 0; i_ < 4; ++i_) {                                      \
        _Pragma("unroll")                                                 \
        for (int q_ = 0; q_ < 4; ++q_) {                                  \
            const float zx_ = ((const float*)&(Z)[i_])[q_];               \
            const int rr_ = i_ * 4 + q_;                                  \
            acc[rr_][0] = fmaf(zx_, (E0).x, acc[rr_][0]);                 \
            acc[rr_][1] = fmaf(zx_, (E0).y, acc[rr_][1]);                 \
            acc[rr_][2] = fmaf(zx_, (E0).z, acc[rr_][2]);                 \
            acc[rr_][3] = fmaf(zx_, (E0).w, acc[rr_][3]);                 \
            acc[rr_][4] = fmaf(zx_, (E1).x, acc[rr_][4]);                 \
            acc[rr_][5] = fmaf(zx_, (E1).y, acc[rr_][5]);                 \
            acc[rr_][6] = fmaf(zx_, (E1).z, acc[rr_][6]);                 \
            acc[rr_][7] = fmaf(zx_, (E1).w, acc[rr_][7]);                 \
        }                                                                 \
    }                                                                     \
} while (0)

#define LOADZ(DST, DD) do {                                              \
    _Pragma("unroll")                                                     \
    for (int i_ = 0; i_ < 4; ++i_)                                        \
        (DST)[i_] = *(const float4*)&ztT[DD][i_ * 4];                     \
} while (0)

#define LOADE(EA, EB, DD) do {                                           \
    const float* p_ = ep + (size_t)(DD) * 8192;                           \
    (EA) = *(const float4*)(p_);                                          \
    (EB) = *(const float4*)(p_ + 4);                                      \
} while (0)

// ---- main: exact-f32-replica distance + argmin.
// 256 thr = 4 waves; 16 rows/block; grid 2048. All waves cover all 16 rows (R=16/thread);
// waves split codes 4-ways within a 2048-code tile: wave w owns w*512..+511, lane j owns
// 8 codes. 3-slot rotation pipeline (unroll-3 body): ef for d+3 issued at position d
// (~768 issue-cycle slack, covers L2/L3 latency, only ~3 loads in flight/wave -> under
// the TCP outstanding-load ceiling that regressed R10); z 3-slot at distance-1 (LDS).
// Per-tile argmin folded into LDS cwd/cwk (full lowest-k tie-break).
// d_nk = fl( fl(sz_n + se_k) - 2*m_nk ),  m = sequential fmaf chain over d=0..255 (BLAS order)
__global__ __launch_bounds__(256, 2) void k_main(
    const float* __restrict__ z, const float* __restrict__ embT,
    const float* __restrict__ se, const float* __restrict__ sz,
    float* __restrict__ idxf, float* __restrict__ lossslot) {
    __shared__ float ztT[256][16];        // [d][row]
    __shared__ float szs[16];
    __shared__ float cwd[4][16];          // [codegrp][row] best distance
    __shared__ int   cwk[4][16];          // matching code id
    const int tid = threadIdx.x;
    const int blk = blockIdx.x;           // grid = 2048
    const int n0  = blk * 16;
    const int b   = n0 >> 10, hw0 = n0 & 1023;

    // stage z tile transposed: ztT[c][n]; coalesced global reads over n;
    // LDS writes 2 lanes/bank (free)
    {
        const int n  = tid & 15;
        const int cg = tid >> 4;                        // 0..15
        const float* zp = z + (size_t)b * 262144 + hw0 + n;
        #pragma unroll
        for (int cc = 0; cc < 256; cc += 16)
            ztT[cc + cg][n] = zp[(size_t)(cc + cg) << 10];
        if (tid < 16) szs[tid] = sz[n0 + tid];
        if (tid < 64) { (&cwd[0][0])[tid] = 3.4e38f; (&cwk[0][0])[tid] = 0; }
    }
    __syncthreads();

    const int w = tid >> 6;       // wave 0..3 -> code quarter w*512 within each tile
    const int j = tid & 63;       // lane -> 8 codes

    for (int tile = 0; tile < 4; ++tile) {
        const int c0 = tile * 2048 + w * 512 + j * 8;
        const float* ep = embT + c0;

        float acc[16][8];
        #pragma unroll
        for (int rr = 0; rr < 16; ++rr)
            #pragma unroll
            for (int c = 0; c < 8; ++c) acc[rr][c] = 0.f;

        // prologue: z slot 0 <- d0; ef slots <- d0, d1, d2
        float4 z0[4], z1[4], z2[4];
        LOADZ(z0, 0);
        float4 e0a, e0b, e1a, e1b, e2a, e2b;
        LOADE(e0a, e0b, 0);
        LOADE(e1a, e1b, 1);
        LOADE(e2a, e2b, 2);

        // invariant entering body at `base`: z0 holds d=base, e_i holds d=base+i
        #pragma unroll 1
        for (int base = 0; base < 255; base += 3) {
            // pos 0: d = base
            LOADZ(z1, base + 1);
            FMA_BLOCK(z0, e0a, e0b);
            LOADE(e0a, e0b, base + 3);
            // pos 1: d = base+1
            LOADZ(z2, base + 2);
            FMA_BLOCK(z1, e1a, e1b);
            LOADE(e1a, e1b, base + 4);
            // pos 2: d = base+2
            LOADZ(z0, base + 3);
            FMA_BLOCK(z2, e2a, e2b);
            LOADE(e2a, e2b, base + 5);
        }
        // tail: d = 255 (z0 loaded at last body pos2; e0 reloaded at last body pos0).
        // Overshoot ef reads (rows 256,257) land in the se/sz scratch region: valid
        // memory, never consumed.
        FMA_BLOCK(z0, e0a, e0b);

        // epilogue: dq = fl( fl(sz+se) - 2m ); codes ascending; strict < keeps first min
        const float4 seA = *(const float4*)(se + c0);
        const float4 seB = *(const float4*)(se + c0 + 4);
        #pragma unroll
        for (int rr = 0; rr < 16; ++rr) {
            const float szv = szs[rr];
            float bd = 3.4e38f; int bk = 0;
            #pragma unroll
            for (int c = 0; c < 8; ++c) {
                const float sek = (c < 4) ? ((const float*)&seA)[c]
                                          : ((const float*)&seB)[c - 4];
                float A  = szv + sek;
                float dq = A - 2.0f * acc[rr][c];
                if (dq < bd) { bd = dq; bk = c0 + c; }
            }
            // butterfly across 64 lanes; tie-break lowest k
            #pragma unroll
            for (int off = 1; off < 64; off <<= 1) {
                float od = __shfl_xor(bd, off);
                int   ok = __shfl_xor(bk, off);
                if (od < bd || (od == bd && ok < bk)) { bd = od; bk = ok; }
            }
            if (j == 0) {
                float pd = cwd[w][rr]; int pk = cwk[w][rr];
                if (bd < pd || (bd == pd && bk < pk)) { cwd[w][rr] = bd; cwk[w][rr] = bk; }
            }
        }
    }
    __syncthreads();
    // merge the 4 code-group partials per row with full (d,k) tie-break
    if (tid < 16) {
        float d = cwd[0][tid]; int k = cwk[0][tid];
        #pragma unroll
        for (int ww = 1; ww < 4; ++ww) {
            float od = cwd[ww][tid]; int ok = cwk[ww][tid];
            if (od < d || (od == d && ok < k)) { d = od; k = ok; }
        }
        idxf[n0 + tid] = (float)k;
    }
    if (blk == 0 && tid == 0) *lossslot = 0.f;   // init loss accumulator (runs before k_out)
}

// ---- z_q (STE-exact) + loss partial sums
__global__ void k_out(const float* __restrict__ z, const float* __restrict__ emb,
                      const float* __restrict__ idxf, float* __restrict__ zq,
                      float* __restrict__ lossslot) {
    int u   = blockIdx.x * 256 + threadIdx.x;   // grid = 8192 blocks (2M threads)
    int cc4 = u >> 15;                          // 0..63 (uniform per block)
    int n   = u & 32767;
    int b   = n >> 10, hw = n & 1023;
    int k   = (int)idxf[n];
    const float4 q4 = *(const float4*)(emb + (size_t)k * 256 + cc4 * 4);
    float ls = 0.f;
    #pragma unroll
    for (int c = 0; c < 4; ++c) {
        size_t zi = (size_t)b * 262144 + (size_t)(cc4 * 4 + c) * 1024 + hw;
        float zv   = z[zi];
        float qv   = ((const float*)&q4)[c];
        float diff = qv - zv;        // fl(q - z)
        zq[zi]     = zv + diff;      // fl(z + fl(q - z))  == reference STE output
        ls += diff * diff;
    }
    #pragma unroll
    for (int off = 1; off < 64; off <<= 1) ls += __shfl_xor(ls, off);
    if ((threadIdx.x & 63) == 0) atomicAdd(lossslot, ls);
}

__global__ void k_fin(float* __restrict__ lossslot) {
    float S = *lossslot;
    float m = S / 8388608.0f;        // /2^23 exact scaling
    *lossslot = m + 0.25f * m;       // fl(m1 + fl(beta*m2)), m1==m2
}

extern "C" void kernel_launch(void* const* d_in, const int* in_sizes, int n_in,
                              void* d_out, int out_size, void* d_ws, size_t ws_size,
                              hipStream_t stream) {
    const float* z   = (const float*)d_in[0];
    const float* emb = (const float*)d_in[1];
    float* out  = (float*)d_out;
    float* embT = out + EMBT_OFF;
    float* se   = out + SE_OFF;
    float* sz   = out + SZ_OFF;
    float* idxf = out + IDX_OFF;
    float* loss = out + LOSS_OFF;

    k_prep<<<10240, 256, 0, stream>>>(emb, embT, se);
    k_sz<<<128, 256, 0, stream>>>(z, sz);
    k_main<<<2048, 256, 0, stream>>>(z, embT, se, sz, idxf, loss);
    k_out<<<8192, 256, 0, stream>>>(z, emb, idxf, out + ZQ_OFF, loss);
    k_fin<<<1, 1, 0, stream>>>(loss);
}

// Round 12
// 1974.070 us; speedup vs baseline: 1.0514x; 1.0080x over previous
//
#include <hip/hip_runtime.h>

// Problem: VQ-VAE codebook. z [32,256,32,32] f32, emb [8192,256] f32.
// Outputs concatenated in d_out (f32): z_q [8388608], idx [32768] (as float), loss [1].
//
// Scratch layout inside d_out's z_q region (consumed before k_out overwrites it):
//   [0 .. 2097152)        embT  (256 x 8192)   transposed codebook
//   [2097152 .. 2105344)  se    (8192)         ||e_k||^2
//   [2105344 .. 2138112)  sz    (32768)        ||z_n||^2
#define ZQ_OFF   0
#define EMBT_OFF 0
#define SE_OFF   2097152
#define SZ_OFF   2105344
#define IDX_OFF  8388608
#define LOSS_OFF 8421376

typedef float f32x2 __attribute__((ext_vector_type(2)));

// ---- fused prep: transpose emb -> embT[d][k]  +  se[k]  +  sz[n]
__global__ void k_prep(const float* __restrict__ emb, float* __restrict__ embT,
                       float* __restrict__ se, const float* __restrict__ z,
                       float* __restrict__ sz) {
    const int blk = blockIdx.x;
    if (blk < 8192) {
        int u = blk * 256 + threadIdx.x;             // 0 .. 2M
        int d = u >> 13;
        int k = u & 8191;
        embT[u] = emb[(size_t)k * 256 + d];
    } else if (blk < 10240) {
        int w    = ((blk - 8192) * 256 + threadIdx.x) >> 6;   // code id
        int lane = threadIdx.x & 63;
        float4 v = *(const float4*)(emb + (size_t)w * 256 + lane * 4);
        float s = v.x * v.x + v.y * v.y + v.z * v.z + v.w * v.w;
        #pragma unroll
        for (int off = 1; off < 64; off <<= 1) s += __shfl_xor(s, off);
        if (lane == 0) se[w] = s;
    } else {
        // sz[n] = sum over c of z[b][c][hw]^2 (sequential chain over c ascending)
        int n  = (blk - 10240) * 256 + threadIdx.x;  // 128 blocks
        int b  = n >> 10, hw = n & 1023;
        const float* zp = z + (size_t)b * 262144 + hw;
        float acc = 0.f;
        #pragma unroll 8
        for (int c = 0; c < 256; ++c) { float v = zp[(size_t)c << 10]; acc += v * v; }
        sz[n] = acc;
    }
}

// packed dual FMA on a row-pair (z pair) x one code; EP holds 2 codes, op_sel picks which.
// even code: D.lo = z.lo*e.lo+acc.lo ; D.hi = z.hi*e.lo+acc.hi
#define PKFMA_EVEN(ACC, ZP, EP) \
    asm("v_pk_fma_f32 %0, %1, %2, %0 op_sel:[0,0,0] op_sel_hi:[1,0,1]" \
        : "+v"(ACC) : "v"(ZP), "v"(EP))
// odd code:  D.lo = z.lo*e.hi+acc.lo ; D.hi = z.hi*e.hi+acc.hi
#define PKFMA_ODD(ACC, ZP, EP) \
    asm("v_pk_fma_f32 %0, %1, %2, %0 op_sel:[0,1,0] op_sel_hi:[1,1,1]" \
        : "+v"(ACC) : "v"(ZP), "v"(EP))

// one d: 16 rows (8 z-pairs) x 8 codes (4 ef-pairs) = 64 pk ops = 128 FMAs.
// Each component is an IEEE fma -> bit-identical to the scalar fmaf chain.
#define FMA_BLOCK(Z, E0, E1) do {                                        \
    f32x2 ep_[4];                                                         \
    ep_[0] = ((const f32x2*)&(E0))[0]; ep_[1] = ((const f32x2*)&(E0))[1]; \
    ep_[2] = ((const f32x2*)&(E1))[0]; ep_[3] = ((const f32x2*)&(E1))[1]; \
    _Pragma("unroll")                                                     \
    for (int p_ = 0; p_ < 8; ++p_) {                                      \
        const f32x2 zp_ = ((const f32x2*)&(Z)[p_ >> 1])[p_ & 1];          \
        _Pragma("unroll")                                                 \
        for (int cp_ = 0; cp_ < 4; ++cp_) {                               \
            PKFMA_EVEN(accp[p_][cp_ * 2],     zp_, ep_[cp_]);             \
            PKFMA_ODD (accp[p_][cp_ * 2 + 1], zp_, ep_[cp_]);             \
        }                                                                 \
    }                                                                     \
} while (0)

#define LOADZ(DST, DD) do {                                              \
    _Pragma("unroll")                                                     \
    for (int i_ = 0; i_ < 4; ++i_)                                        \
        (DST)[i_] = *(const float4*)&ztT[DD][i_ * 4];                     \
} while (0)

#define LOADE(EA, EB, DD) do {                                           \
    const float* p_ = ep + (size_t)(DD) * 8192;                           \
    (EA) = *(const float4*)(p_);                                          \
    (EB) = *(const float4*)(p_ + 4);                                      \
} while (0)

// ---- main: exact-f32-replica distance + argmin.
// Structure identical to R11 (3-slot rotation pipeline, 4-way code split, 16 rows/block,
// grid 2048) except the inner FMA block uses v_pk_fma_f32 row-pairs: acc = f32x2[8][8]
// (rows 2p,2p+1 x code c). z pairs come free from the float4 LDS loads; ef lo/hi chosen
// by op_sel -> no marshalling movs. Per-tile argmin folded into LDS cwd/cwk.
// d_nk = fl( fl(sz_n + se_k) - 2*m_nk ),  m = sequential fmaf chain over d=0..255 (BLAS order)
__global__ __launch_bounds__(256, 2) void k_main(
    const float* __restrict__ z, const float* __restrict__ embT,
    const float* __restrict__ se, const float* __restrict__ sz,
    float* __restrict__ idxf, float* __restrict__ lossslot) {
    __shared__ float ztT[256][16];        // [d][row]
    __shared__ float szs[16];
    __shared__ float cwd[4][16];          // [codegrp][row] best distance
    __shared__ int   cwk[4][16];          // matching code id
    const int tid = threadIdx.x;
    const int blk = blockIdx.x;           // grid = 2048
    const int n0  = blk * 16;
    const int b   = n0 >> 10, hw0 = n0 & 1023;

    // stage z tile transposed: ztT[c][n]; coalesced global reads over n
    {
        const int n  = tid & 15;
        const int cg = tid >> 4;                        // 0..15
        const float* zp = z + (size_t)b * 262144 + hw0 + n;
        #pragma unroll
        for (int cc = 0; cc < 256; cc += 16)
            ztT[cc + cg][n] = zp[(size_t)(cc + cg) << 10];
        if (tid < 16) szs[tid] = sz[n0 + tid];
        if (tid < 64) { (&cwd[0][0])[tid] = 3.4e38f; (&cwk[0][0])[tid] = 0; }
    }
    __syncthreads();

    const int w = tid >> 6;       // wave 0..3 -> code quarter w*512 within each tile
    const int j = tid & 63;       // lane -> 8 codes

    for (int tile = 0; tile < 4; ++tile) {
        const int c0 = tile * 2048 + w * 512 + j * 8;
        const float* ep = embT + c0;

        f32x2 accp[8][8];
        #pragma unroll
        for (int p = 0; p < 8; ++p)
            #pragma unroll
            for (int c = 0; c < 8; ++c) { accp[p][c].x = 0.f; accp[p][c].y = 0.f; }

        // prologue: z slot 0 <- d0; ef slots <- d0, d1, d2
        float4 z0[4], z1[4], z2[4];
        LOADZ(z0, 0);
        float4 e0a, e0b, e1a, e1b, e2a, e2b;
        LOADE(e0a, e0b, 0);
        LOADE(e1a, e1b, 1);
        LOADE(e2a, e2b, 2);

        // invariant entering body at `base`: z0 holds d=base, e_i holds d=base+i
        #pragma unroll 1
        for (int base = 0; base < 255; base += 3) {
            // pos 0: d = base
            LOADZ(z1, base + 1);
            FMA_BLOCK(z0, e0a, e0b);
            LOADE(e0a, e0b, base + 3);
            // pos 1: d = base+1
            LOADZ(z2, base + 2);
            FMA_BLOCK(z1, e1a, e1b);
            LOADE(e1a, e1b, base + 4);
            // pos 2: d = base+2
            LOADZ(z0, base + 3);
            FMA_BLOCK(z2, e2a, e2b);
            LOADE(e2a, e2b, base + 5);
        }
        // tail: d = 255. Overshoot ef reads (rows 256,257) land in the se/sz scratch
        // region (valid memory, never consumed); LOADZ(z0,255) from last body pos2.
        FMA_BLOCK(z0, e0a, e0b);

        // epilogue: dq = fl( fl(sz+se) - 2m ); codes ascending; strict < keeps first min
        const float4 seA = *(const float4*)(se + c0);
        const float4 seB = *(const float4*)(se + c0 + 4);
        #pragma unroll
        for (int rr = 0; rr < 16; ++rr) {
            const float szv = szs[rr];
            float bd = 3.4e38f; int bk = 0;
            #pragma unroll
            for (int c = 0; c < 8; ++c) {
                const float sek = (c < 4) ? ((const float*)&seA)[c]
                                          : ((const float*)&seB)[c - 4];
                const float m  = (rr & 1) ? accp[rr >> 1][c].y : accp[rr >> 1][c].x;
                float A  = szv + sek;
                float dq = A - 2.0f * m;
                if (dq < bd) { bd = dq; bk = c0 + c; }
            }
            // butterfly across 64 lanes; tie-break lowest k
            #pragma unroll
            for (int off = 1; off < 64; off <<= 1) {
                float od = __shfl_xor(bd, off);
                int   ok = __shfl_xor(bk, off);
                if (od < bd || (od == bd && ok < bk)) { bd = od; bk = ok; }
            }
            if (j == 0) {
                float pd = cwd[w][rr]; int pk = cwk[w][rr];
                if (bd < pd || (bd == pd && bk < pk)) { cwd[w][rr] = bd; cwk[w][rr] = bk; }
            }
        }
    }
    __syncthreads();
    // merge the 4 code-group partials per row with full (d,k) tie-break
    if (tid < 16) {
        float d = cwd[0][tid]; int k = cwk[0][tid];
        #pragma unroll
        for (int ww = 1; ww < 4; ++ww) {
            float od = cwd[ww][tid]; int ok = cwk[ww][tid];
            if (od < d || (od == d && ok < k)) { d = od; k = ok; }
        }
        idxf[n0 + tid] = (float)k;
    }
    if (blk == 0 && tid == 0) *lossslot = 0.f;   // init loss accumulator (runs before k_out)
}

// ---- z_q (STE-exact) + loss partial sums
__global__ void k_out(const float* __restrict__ z, const float* __restrict__ emb,
                      const float* __restrict__ idxf, float* __restrict__ zq,
                      float* __restrict__ lossslot) {
    int u   = blockIdx.x * 256 + threadIdx.x;   // grid = 8192 blocks (2M threads)
    int cc4 = u >> 15;                          // 0..63 (uniform per block)
    int n   = u & 32767;
    int b   = n >> 10, hw = n & 1023;
    int k   = (int)idxf[n];
    const float4 q4 = *(const float4*)(emb + (size_t)k * 256 + cc4 * 4);
    float ls = 0.f;
    #pragma unroll
    for (int c = 0; c < 4; ++c) {
        size_t zi = (size_t)b * 262144 + (size_t)(cc4 * 4 + c) * 1024 + hw;
        float zv   = z[zi];
        float qv   = ((const float*)&q4)[c];
        float diff = qv - zv;        // fl(q - z)
        zq[zi]     = zv + diff;      // fl(z + fl(q - z))  == reference STE output
        ls += diff * diff;
    }
    #pragma unroll
    for (int off = 1; off < 64; off <<= 1) ls += __shfl_xor(ls, off);
    if ((threadIdx.x & 63) == 0) atomicAdd(lossslot, ls);
}

__global__ void k_fin(float* __restrict__ lossslot) {
    float S = *lossslot;
    float m = S / 8388608.0f;        // /2^23 exact scaling
    *lossslot = m + 0.25f * m;       // fl(m1 + fl(beta*m2)), m1==m2
}

extern "C" void kernel_launch(void* const* d_in, const int* in_sizes, int n_in,
                              void* d_out, int out_size, void* d_ws, size_t ws_size,
                              hipStream_t stream) {
    const float* z   = (const float*)d_in[0];
    const float* emb = (const float*)d_in[1];
    float* out  = (float*)d_out;
    float* embT = out + EMBT_OFF;
    float* se   = out + SE_OFF;
    float* sz   = out + SZ_OFF;
    float* idxf = out + IDX_OFF;
    float* loss = out + LOSS_OFF;

    k_prep<<<10368, 256, 0, stream>>>(emb, embT, se, z, sz);
    k_main<<<2048, 256, 0, stream>>>(z, embT, se, sz, idxf, loss);
    k_out<<<8192, 256, 0, stream>>>(z, emb, idxf, out + ZQ_OFF, loss);
    k_fin<<<1, 1, 0, stream>>>(loss);
}